// Round 1
// baseline (444.550 us; speedup 1.0000x reference)
//
#include <hip/hip_runtime.h>
#include <hip/hip_bf16.h>

#define TSEQ 4096
#define EMB 768
#define NH 12
#define DH 64
#define BT 8192  // B*T

typedef __attribute__((ext_vector_type(8))) short bf16x8;
typedef __attribute__((ext_vector_type(4))) float f32x4;

__device__ inline f32x4 mfma16(bf16x8 a, bf16x8 b, f32x4 c) {
    return __builtin_amdgcn_mfma_f32_16x16x32_bf16(a, b, c, 0, 0, 0);
}

// ---------- conversion kernels ----------
__global__ __launch_bounds__(256) void conv_x_k(const float* __restrict__ x,
                                                __hip_bfloat16* __restrict__ xb) {
    int i = (blockIdx.x * 256 + threadIdx.x) * 4;
    float4 v = *(const float4*)(x + i);
    union { unsigned short u[4]; uint2 p; } o;
    __hip_bfloat16 t0 = __float2bfloat16(v.x); o.u[0] = *(unsigned short*)&t0;
    __hip_bfloat16 t1 = __float2bfloat16(v.y); o.u[1] = *(unsigned short*)&t1;
    __hip_bfloat16 t2 = __float2bfloat16(v.z); o.u[2] = *(unsigned short*)&t2;
    __hip_bfloat16 t3 = __float2bfloat16(v.w); o.u[3] = *(unsigned short*)&t3;
    *(uint2*)(xb + i) = o.p;
}

// transpose 768x768 fp32 (k,n) -> bf16 (n,k); z selects which weight
__global__ __launch_bounds__(256) void conv_w_k(const float* w0, const float* w1,
                                                const float* w2, const float* w3,
                                                __hip_bfloat16* o0, __hip_bfloat16* o1,
                                                __hip_bfloat16* o2, __hip_bfloat16* o3) {
    const float* w; __hip_bfloat16* o;
    switch (blockIdx.z) {
        case 0: w = w0; o = o0; break;
        case 1: w = w1; o = o1; break;
        case 2: w = w2; o = o2; break;
        default: w = w3; o = o3; break;
    }
    __shared__ float tile[32][33];
    int tx = threadIdx.x & 31, ty = threadIdx.x >> 5;  // 32 x 8
    int kb = blockIdx.y * 32, nb = blockIdx.x * 32;
    for (int i = 0; i < 32; i += 8)
        tile[ty + i][tx] = w[(size_t)(kb + ty + i) * EMB + nb + tx];
    __syncthreads();
    for (int i = 0; i < 32; i += 8)
        o[(size_t)(nb + ty + i) * EMB + kb + tx] = __float2bfloat16(tile[tx][ty + i]);
}

// ---------- GEMM: C(M,N) = A(M,K) * Wt(N,K)^T + bias ----------
// MODE 0: write bf16 (B,H,T,D)   (Q, K)
// MODE 1: write bf16 (B,H,D,T)   (V transposed)
// MODE 2: write fp32 row-major (M,N) with bias (final output)
template<int MODE>
__global__ __launch_bounds__(256) void gemm_k(const __hip_bfloat16* __restrict__ A,
                                              const __hip_bfloat16* __restrict__ Wt,
                                              const float* __restrict__ bias,
                                              void* __restrict__ outp) {
    __shared__ __hip_bfloat16 As[128 * 32];
    __shared__ __hip_bfloat16 Bs[128 * 32];
    const int m0 = blockIdx.x * 128, n0 = blockIdx.y * 128;
    const int tid = threadIdx.x;
    const int lane = tid & 63, l15 = lane & 15, lg = lane >> 4;
    const int wave = tid >> 6, wm = wave >> 1, wn = wave & 1;
    const int sr = tid >> 2, sc = (tid & 3) << 3;

    f32x4 acc[4][4];
    for (int i = 0; i < 4; ++i)
        for (int j = 0; j < 4; ++j) acc[i][j] = (f32x4){0.f, 0.f, 0.f, 0.f};

    for (int k0 = 0; k0 < EMB; k0 += 32) {
        bf16x8 a0 = *(const bf16x8*)(A + (size_t)(m0 + sr) * EMB + k0 + sc);
        bf16x8 a1 = *(const bf16x8*)(A + (size_t)(m0 + sr + 64) * EMB + k0 + sc);
        bf16x8 b0 = *(const bf16x8*)(Wt + (size_t)(n0 + sr) * EMB + k0 + sc);
        bf16x8 b1 = *(const bf16x8*)(Wt + (size_t)(n0 + sr + 64) * EMB + k0 + sc);
        __syncthreads();
        *(bf16x8*)(As + sr * 32 + sc) = a0;
        *(bf16x8*)(As + (sr + 64) * 32 + sc) = a1;
        *(bf16x8*)(Bs + sr * 32 + sc) = b0;
        *(bf16x8*)(Bs + (sr + 64) * 32 + sc) = b1;
        __syncthreads();
        bf16x8 af[4], bfv[4];
#pragma unroll
        for (int f = 0; f < 4; ++f)
            af[f] = *(const bf16x8*)(As + (wm * 64 + f * 16 + l15) * 32 + lg * 8);
#pragma unroll
        for (int f = 0; f < 4; ++f)
            bfv[f] = *(const bf16x8*)(Bs + (wn * 64 + f * 16 + l15) * 32 + lg * 8);
#pragma unroll
        for (int i = 0; i < 4; ++i)
#pragma unroll
            for (int j = 0; j < 4; ++j)
                acc[i][j] = mfma16(af[i], bfv[j], acc[i][j]);
    }

#pragma unroll
    for (int i = 0; i < 4; ++i) {
#pragma unroll
        for (int j = 0; j < 4; ++j) {
            const int n = n0 + wn * 64 + j * 16 + l15;
            const float bv = bias[n];
            const int mbase = m0 + wm * 64 + i * 16 + lg * 4;
#pragma unroll
            for (int r = 0; r < 4; ++r) {
                const int m = mbase + r;
                const float val = acc[i][j][r] + bv;
                if (MODE == 2) {
                    ((float*)outp)[(size_t)m * EMB + n] = val;
                } else {
                    const int b = m >> 12, t = m & (TSEQ - 1);
                    const int h = n >> 6, d = n & 63;
                    size_t addr;
                    if (MODE == 0) addr = ((size_t)(b * NH + h) * TSEQ + t) * DH + d;
                    else           addr = ((size_t)(b * NH + h) * DH + d) * TSEQ + t;
                    ((__hip_bfloat16*)outp)[addr] = __float2bfloat16(val);
                }
            }
        }
    }
}

// ---------- flash attention ----------
// Q,K: (B,H,T,D) bf16.  V: (B,H,D,T) bf16 (transposed).  out ab: (B,T,E) bf16.
// 4 waves/block, each wave owns 32 q-rows; s-blocks of 64.
// S^T = K*Q^T so softmax is per-lane-column; P transposed via per-wave LDS bounce.
__global__ __launch_bounds__(256) void attn_k(const __hip_bfloat16* __restrict__ qb,
                                              const __hip_bfloat16* __restrict__ kb,
                                              const __hip_bfloat16* __restrict__ vt,
                                              __hip_bfloat16* __restrict__ ab) {
    __shared__ __hip_bfloat16 pn[4][16 * 72];  // per-wave P buffer, stride 72 (16B-aligned rows)
    const int bh = blockIdx.y;
    const int lane = threadIdx.x & 63, l15 = lane & 15, lg = lane >> 4;
    const int wave = threadIdx.x >> 6;
    const int q0 = blockIdx.x * 128 + wave * 32;
    const __hip_bfloat16* Qh = qb + (size_t)bh * TSEQ * DH;
    const __hip_bfloat16* Kh = kb + (size_t)bh * TSEQ * DH;
    const __hip_bfloat16* Vh = vt + (size_t)bh * DH * TSEQ;
    __hip_bfloat16* P = pn[wave];
    const float c = 0.125f * 1.44269504089f;  // scale * log2(e) folded into exp2

    bf16x8 qf[2][2];
#pragma unroll
    for (int qt = 0; qt < 2; ++qt)
#pragma unroll
        for (int ks = 0; ks < 2; ++ks)
            qf[qt][ks] = *(const bf16x8*)(Qh + (size_t)(q0 + qt * 16 + l15) * DH + ks * 32 + lg * 8);

    f32x4 o[2][4];
    for (int qt = 0; qt < 2; ++qt)
        for (int dt = 0; dt < 4; ++dt) o[qt][dt] = (f32x4){0.f, 0.f, 0.f, 0.f};
    float mrow[2] = {-INFINITY, -INFINITY};
    float lrow[2] = {0.f, 0.f};

    const int nsb = ((q0 + 31) >> 6) + 1;
    for (int sb = 0; sb < nsb; ++sb) {
        const int s0 = sb * 64;
        const bool maskneed = (s0 + 63 > q0);
        bf16x8 kf[4][2], vf[4][2];
#pragma unroll
        for (int st = 0; st < 4; ++st)
#pragma unroll
            for (int ks = 0; ks < 2; ++ks)
                kf[st][ks] = *(const bf16x8*)(Kh + (size_t)(s0 + st * 16 + l15) * DH + ks * 32 + lg * 8);
#pragma unroll
        for (int dt = 0; dt < 4; ++dt)
#pragma unroll
            for (int ks = 0; ks < 2; ++ks)
                vf[dt][ks] = *(const bf16x8*)(Vh + (size_t)(dt * 16 + l15) * TSEQ + s0 + ks * 32 + lg * 8);

#pragma unroll
        for (int qt = 0; qt < 2; ++qt) {
            // S^T tiles: rows = s (4 per lane per tile), col = q = l15
            f32x4 sa[4];
#pragma unroll
            for (int st = 0; st < 4; ++st) {
                f32x4 z = (f32x4){0.f, 0.f, 0.f, 0.f};
                z = mfma16(kf[st][0], qf[qt][0], z);
                z = mfma16(kf[st][1], qf[qt][1], z);
                sa[st] = z;
            }
            const int q = q0 + qt * 16 + l15;
            if (maskneed) {
#pragma unroll
                for (int st = 0; st < 4; ++st)
#pragma unroll
                    for (int r = 0; r < 4; ++r)
                        if (s0 + st * 16 + lg * 4 + r > q) sa[st][r] = -INFINITY;
            }
            float mx = -INFINITY;
#pragma unroll
            for (int st = 0; st < 4; ++st)
#pragma unroll
                for (int r = 0; r < 4; ++r) mx = fmaxf(mx, sa[st][r]);
            mx = fmaxf(mx, __shfl_xor(mx, 16));
            mx = fmaxf(mx, __shfl_xor(mx, 32));
            const float mnew = fmaxf(mrow[qt], mx);

            float sum = 0.f;
#pragma unroll
            for (int st = 0; st < 4; ++st) {
                union { unsigned short u[4]; uint2 v; } pk;
#pragma unroll
                for (int r = 0; r < 4; ++r) {
                    const float p = exp2f((sa[st][r] - mnew) * c);
                    sum += p;
                    __hip_bfloat16 hb = __float2bfloat16(p);
                    pk.u[r] = *(unsigned short*)&hb;
                }
                *(uint2*)(P + l15 * 72 + st * 16 + lg * 4) = pk.v;
            }
            sum += __shfl_xor(sum, 16);
            sum += __shfl_xor(sum, 32);
            const float rescale = exp2f((mrow[qt] - mnew) * c);
            lrow[qt] = lrow[qt] * rescale + sum;
            mrow[qt] = mnew;

            float fr[4];
#pragma unroll
            for (int r = 0; r < 4; ++r) fr[r] = __shfl(rescale, lg * 4 + r);
#pragma unroll
            for (int dt = 0; dt < 4; ++dt) {
                f32x4 ov = o[qt][dt];
#pragma unroll
                for (int r = 0; r < 4; ++r) ov[r] *= fr[r];
                o[qt][dt] = ov;
            }

            asm volatile("s_waitcnt lgkmcnt(0)" ::: "memory");  // P writes visible wave-wide
#pragma unroll
            for (int ks = 0; ks < 2; ++ks) {
                bf16x8 pf = *(const bf16x8*)(P + l15 * 72 + ks * 32 + lg * 8);
#pragma unroll
                for (int dt = 0; dt < 4; ++dt)
                    o[qt][dt] = mfma16(pf, vf[dt][ks], o[qt][dt]);
            }
            asm volatile("s_waitcnt lgkmcnt(0)" ::: "memory");  // P reads done before next qt overwrites
        }
    }

    const int b = bh / NH, h = bh % NH;
#pragma unroll
    for (int qt = 0; qt < 2; ++qt) {
        const float linv = 1.0f / lrow[qt];
        float lr[4];
#pragma unroll
        for (int r = 0; r < 4; ++r) lr[r] = __shfl(linv, lg * 4 + r);
#pragma unroll
        for (int r = 0; r < 4; ++r) {
            const int q = q0 + qt * 16 + lg * 4 + r;
            const size_t rowbase = ((size_t)b * TSEQ + q) * EMB + h * DH;
#pragma unroll
            for (int dt = 0; dt < 4; ++dt)
                ab[rowbase + dt * 16 + l15] = __float2bfloat16(o[qt][dt][r] * lr[r]);
        }
    }
}

extern "C" void kernel_launch(void* const* d_in, const int* in_sizes, int n_in,
                              void* d_out, int out_size, void* d_ws, size_t ws_size,
                              hipStream_t stream) {
    (void)in_sizes; (void)n_in; (void)out_size; (void)ws_size;
    const float* x  = (const float*)d_in[0];
    const float* wq = (const float*)d_in[1];
    const float* bq = (const float*)d_in[2];
    const float* wk = (const float*)d_in[3];
    const float* bk = (const float*)d_in[4];
    const float* wv = (const float*)d_in[5];
    const float* bv = (const float*)d_in[6];
    const float* wo = (const float*)d_in[7];
    const float* bo = (const float*)d_in[8];
    float* out = (float*)d_out;

    char* ws = (char*)d_ws;
    size_t off = 0;
    auto alloc = [&](size_t bytes) {
        char* p = ws + off;
        off += (bytes + 255) & ~(size_t)255;
        return p;
    };
    __hip_bfloat16* xb  = (__hip_bfloat16*)alloc((size_t)BT * EMB * 2);
    __hip_bfloat16* qbf = (__hip_bfloat16*)alloc((size_t)BT * EMB * 2);
    __hip_bfloat16* kbf = (__hip_bfloat16*)alloc((size_t)BT * EMB * 2);
    __hip_bfloat16* vtb = (__hip_bfloat16*)alloc((size_t)BT * EMB * 2);
    __hip_bfloat16* abf = (__hip_bfloat16*)alloc((size_t)BT * EMB * 2);
    __hip_bfloat16* wqT = (__hip_bfloat16*)alloc((size_t)EMB * EMB * 2);
    __hip_bfloat16* wkT = (__hip_bfloat16*)alloc((size_t)EMB * EMB * 2);
    __hip_bfloat16* wvT = (__hip_bfloat16*)alloc((size_t)EMB * EMB * 2);
    __hip_bfloat16* woT = (__hip_bfloat16*)alloc((size_t)EMB * EMB * 2);

    conv_x_k<<<BT * EMB / 1024, 256, 0, stream>>>(x, xb);
    conv_w_k<<<dim3(24, 24, 4), 256, 0, stream>>>(wq, wk, wv, wo, wqT, wkT, wvT, woT);
    gemm_k<0><<<dim3(64, 6), 256, 0, stream>>>(xb, wqT, bq, qbf);
    gemm_k<0><<<dim3(64, 6), 256, 0, stream>>>(xb, wkT, bk, kbf);
    gemm_k<1><<<dim3(64, 6), 256, 0, stream>>>(xb, wvT, bv, vtb);
    attn_k<<<dim3(TSEQ / 128, 24), 256, 0, stream>>>(qbf, kbf, vtb, abf);
    gemm_k<2><<<dim3(64, 6), 256, 0, stream>>>(abf, woT, bo, out);
}